// Round 17
// baseline (412.332 us; speedup 1.0000x reference)
//
#include <hip/hip_runtime.h>

#define NN 100000
#define EE 1600000
#define IND 512
#define HIDD 128
#define OUTD 16
#define DEG_BLKS 192
#define GEMM_BLKS 1563  // ceil(NN/64)

typedef __bf16 bf16x8 __attribute__((ext_vector_type(8)));
typedef float f32x4 __attribute__((ext_vector_type(4)));

__device__ __forceinline__ ushort f2bf(float f) {
    union { float f; uint u; } v; v.f = f;
    uint r = v.u + 0x7FFFu + ((v.u >> 16) & 1u);
    return (ushort)(r >> 16);
}

__device__ __forceinline__ uint pk2bf(float a, float b) {
    __bf16 x = (__bf16)a, y = (__bf16)b;
    ushort ux = *(ushort*)&x, uy = *(ushort*)&y;
    return (uint)ux | ((uint)uy << 16);
}

#define GLDS16(src, dst)                                              \
    __builtin_amdgcn_global_load_lds(                                 \
        (const __attribute__((address_space(1))) void*)(src),         \
        (__attribute__((address_space(3))) void*)(dst), 16, 0, 0)

// ---------------- W prep ----------------
__global__ void k_prep(const float* __restrict__ W1, const float* __restrict__ W2,
                       ushort* __restrict__ Wt1, ushort* __restrict__ Wt2) {
    int b = blockIdx.x, tid = threadIdx.x;
    if (b < 256) {
        int i = b * 256 + tid;
        int k = i >> 7, n = i & 127;
        Wt1[n * 512 + k] = f2bf(W1[i]);
    } else {
        int i = (b - 256) * 256 + tid;
        int k = i >> 7, n = i & 127;
        Wt2[n * 128 + k] = f2bf(W2[i]);
    }
}

// ---------------- scan (3 phases; norm fused into final) ----------------
__global__ void k_scan_local(const int* __restrict__ deg, int* __restrict__ incl,
                             int* __restrict__ bsum) {
    __shared__ int s[256];
    int tid = threadIdx.x;
    int i = blockIdx.x * 256 + tid;
    int v = (i < NN) ? deg[i] : 0;
    s[tid] = v;
    __syncthreads();
    for (int off = 1; off < 256; off <<= 1) {
        int t = (tid >= off) ? s[tid - off] : 0;
        __syncthreads();
        s[tid] += t;
        __syncthreads();
    }
    if (i < NN) incl[i] = s[tid];
    if (tid == 255) bsum[blockIdx.x] = s[255];
}

__global__ void k_scan_bsum(const int* __restrict__ bsum, int* __restrict__ boff, int n) {
    __shared__ int s[512];
    int tid = threadIdx.x;
    int v = (tid < n) ? bsum[tid] : 0;
    s[tid] = v;
    __syncthreads();
    for (int off = 1; off < 512; off <<= 1) {
        int t = (tid >= off) ? s[tid - off] : 0;
        __syncthreads();
        s[tid] += t;
        __syncthreads();
    }
    if (tid < n) boff[tid] = s[tid] - v;  // exclusive
}

__global__ void k_scan_final(const int* __restrict__ incl, const int* __restrict__ deg,
                             const int* __restrict__ boff, int* __restrict__ rs,
                             float* __restrict__ dis, float* __restrict__ dinv) {
    int i = blockIdx.x * 256 + threadIdx.x;
    if (i < NN) {
        int d = deg[i];
        int v = incl[i] + boff[i >> 8];
        rs[i] = v - d;
        if (i == NN - 1) rs[NN] = v;
        float df = (float)(d + 1);
        dis[i] = rsqrtf(df);
        dinv[i] = 1.0f / df;
    }
}

// ---------------- CSR fill: atomic-free ----------------
__global__ void k_fill(const int* __restrict__ src, const int* __restrict__ dst,
                       const int* __restrict__ pos, const int* __restrict__ rs,
                       const float* __restrict__ dis, int2* __restrict__ ew) {
    int i = blockIdx.x * blockDim.x + threadIdx.x;
    int stride = gridDim.x * blockDim.x;
    for (; i < EE; i += stride) {
        int d = dst[i];
        int s = src[i];
        ew[rs[d] + pos[i]] = make_int2(s, __float_as_int(dis[s] * dis[d]));
    }
}

// ---------------- bf16 MFMA GEMM body: A via DMA-dbuf LDS, W via per-lane global ----------------
// BM=64, BK=32, 4 waves (wave w -> rows w*16..15, all 128 cols).
// Per k-step: (1) issue W_t fragment loads (per-lane, L2-hot, into regs),
// (2) sched_barrier pins order, (3) DMA-stage A(t+1), (4) vmcnt(N)=t+1's A calls
// -> implies W_t and A_t complete (FIFO), (5) barrier, MFMA.
// LDS = 2 x A-tile only (16KB fp32 / 8KB bf16).
template <int K, bool AFP32>
__device__ __forceinline__ void gemm_body(const void* __restrict__ Ap,
                                          const ushort* __restrict__ Wt,
                                          ushort* __restrict__ C, int M, int blk) {
    constexpr int NT = K / 32;
    constexpr int ABYTES = AFP32 ? 64 * 32 * 4 : 64 * 32 * 2;
    __shared__ char smem[2 * ABYTES];

    int tid = threadIdx.x;
    int row0 = blk * 64;
    int wid = tid >> 6, lane = tid & 63;
    int wm = wid * 16;
    int lm = lane & 15, lk8 = (lane >> 4) * 8;

    const float* Af = (const float*)Ap;
    const ushort* Ab16 = (const ushort*)Ap;
    const ushort* Wl0 = Wt + (size_t)lm * K + lk8;  // row lm, +q*16 rows per frag

    f32x4 acc[8];
#pragma unroll
    for (int q = 0; q < 8; q++) acc[q] = (f32x4){0.f, 0.f, 0.f, 0.f};

    auto stage = [&](int bi, int k0) {
        char* Abase = smem + bi * ABYTES;
        if (AFP32) {
#pragma unroll
            for (int j = 0; j < 2; j++) {
                int c = wid * 2 + j;
                int rp = c * 8 + (lane >> 3);
                int sl = (lane & 7) ^ (rp & 7);
                int gr2 = row0 + rp; if (gr2 >= M) gr2 = M - 1;
                GLDS16(Af + (size_t)gr2 * K + k0 + sl * 4, Abase + c * 1024);
            }
        } else {
            int c = wid;
            int rp = c * 16 + (lane >> 2);
            int sl = (lane & 3) ^ (rp & 3);
            int gr2 = row0 + rp; if (gr2 >= M) gr2 = M - 1;
            GLDS16(Ab16 + (size_t)gr2 * K + k0 + sl * 8, Abase + c * 1024);
        }
    };

    stage(0, 0);

    int cur = 0;
    for (int t = 0; t < NT; t++) {
        // (1) W fragments for tile t: per-lane 16B loads, L2-hot
        bf16x8 wf[8];
#pragma unroll
        for (int q = 0; q < 8; q++)
            wf[q] = *(const bf16x8*)(Wl0 + (size_t)q * 16 * K + t * 32);
        __builtin_amdgcn_sched_barrier(0);  // pin: W loads issue before A-DMA

        // (2) prefetch A(t+1); counted wait leaves it in flight
        if (t + 1 < NT) {
            stage((t + 1) & 1, (t + 1) * 32);
            if (AFP32) asm volatile("s_waitcnt vmcnt(2)" ::: "memory");
            else       asm volatile("s_waitcnt vmcnt(1)" ::: "memory");
        } else {
            asm volatile("s_waitcnt vmcnt(0)" ::: "memory");
        }
        __builtin_amdgcn_s_barrier();  // A(t) visible to all waves

        char* Abase = smem + cur * ABYTES;
        bf16x8 xf;
        if (AFP32) {
            int r_ = wm + lm;
            int s0 = lk8 >> 2;
            f32x4 a0 = *(const f32x4*)(Abase + r_ * 128 + (((s0)     ^ (r_ & 7)) << 4));
            f32x4 a1 = *(const f32x4*)(Abase + r_ * 128 + (((s0 + 1) ^ (r_ & 7)) << 4));
            uint4 u;
            u.x = pk2bf(a0[0], a0[1]);
            u.y = pk2bf(a0[2], a0[3]);
            u.z = pk2bf(a1[0], a1[1]);
            u.w = pk2bf(a1[2], a1[3]);
            xf = *(bf16x8*)&u;
        } else {
            int r_ = wm + lm;
            int s = lk8 >> 3;
            uint4 u = *(const uint4*)(Abase + r_ * 64 + ((s ^ (r_ & 3)) << 4));
            xf = *(bf16x8*)&u;
        }
#pragma unroll
        for (int q = 0; q < 8; q++)
            acc[q] = __builtin_amdgcn_mfma_f32_16x16x32_bf16(wf[q], xf, acc[q], 0, 0, 0);

        asm volatile("" ::: "memory");
        __builtin_amdgcn_s_barrier();  // all waves done reading A(t)
        cur ^= 1;
    }

    int cn4 = (lane >> 4) * 4;
    int m = row0 + wm + lm;
    if (m < M) {
#pragma unroll
        for (int q = 0; q < 8; q++) {
            int n = q * 16 + cn4;
            uint2 o;
            o.x = (uint)f2bf(acc[q][0]) | ((uint)f2bf(acc[q][1]) << 16);
            o.y = (uint)f2bf(acc[q][2]) | ((uint)f2bf(acc[q][3]) << 16);
            *(uint2*)(C + (size_t)m * 128 + n) = o;
        }
    }
}

// mega1: blocks [0,DEG_BLKS) do deg+pos; rest do GEMM1.
__global__ __launch_bounds__(256, 5) void k_mega1(const float* __restrict__ x,
                                                  const ushort* __restrict__ Wt1,
                                                  ushort* __restrict__ C,
                                                  const int* __restrict__ dst,
                                                  int* __restrict__ deg,
                                                  int* __restrict__ pos) {
    if (blockIdx.x < DEG_BLKS) {
        int i = blockIdx.x * 256 + threadIdx.x;
        int stride = DEG_BLKS * 256;
        for (; i < EE; i += stride) pos[i] = atomicAdd(&deg[dst[i]], 1);
    } else {
        gemm_body<IND, true>(x, Wt1, C, NN, blockIdx.x - DEG_BLKS);
    }
}

__global__ __launch_bounds__(256, 6) void k_gemm2(const ushort* __restrict__ A,
                                                  const ushort* __restrict__ Wt,
                                                  ushort* __restrict__ C) {
    gemm_body<HIDD, false>(A, Wt, C, NN, blockIdx.x);
}

// ---------------- aggregation over bf16 h (half-wave pairing) ----------------
template <bool OUTF32>
__global__ __launch_bounds__(256) void k_agg(const ushort* __restrict__ h,
                                             const int* __restrict__ rs,
                                             const int2* __restrict__ ew,
                                             const float* __restrict__ dinv,
                                             const float* __restrict__ bias,
                                             void* __restrict__ yv) {
    int node = blockIdx.x * 4 + (threadIdx.x >> 6);
    int lane = threadIdx.x & 63;
    if (node >= NN) return;
    int half = lane >> 5, c = lane & 31;
    const uint2* h64 = (const uint2*)h;

    float acc0 = 0.f, acc1 = 0.f, acc2 = 0.f, acc3 = 0.f;
    if (half == 0) {
        float dv = dinv[node];
        uint2 sv = h64[(size_t)node * 32 + c];
        acc0 = __uint_as_float(sv.x << 16) * dv;
        acc1 = __uint_as_float(sv.x & 0xffff0000u) * dv;
        acc2 = __uint_as_float(sv.y << 16) * dv;
        acc3 = __uint_as_float(sv.y & 0xffff0000u) * dv;
    }

    int e = rs[node], e1 = rs[node + 1];

#define EL(i) int2 p##i = ew[e + 2 * i + half]; \
              uint2 g##i = h64[(size_t)(uint)p##i.x * 32 + c];
#define EA(i) { float w##i = __int_as_float(p##i.y); \
    acc0 += w##i * __uint_as_float(g##i.x << 16); \
    acc1 += w##i * __uint_as_float(g##i.x & 0xffff0000u); \
    acc2 += w##i * __uint_as_float(g##i.y << 16); \
    acc3 += w##i * __uint_as_float(g##i.y & 0xffff0000u); }

    for (; e + 16 <= e1; e += 16) {
        EL(0) EL(1) EL(2) EL(3) EL(4) EL(5) EL(6) EL(7)
        EA(0) EA(1) EA(2) EA(3) EA(4) EA(5) EA(6) EA(7)
    }
    for (; e + 4 <= e1; e += 4) {
        EL(0) EL(1)
        EA(0) EA(1)
    }
    if (e + 2 <= e1) {
        EL(0)
        EA(0)
        e += 2;
    }
    if (e < e1 && half == 0) {
        int2 p = ew[e];
        uint2 g = h64[(size_t)(uint)p.x * 32 + c];
        float w = __int_as_float(p.y);
        acc0 += w * __uint_as_float(g.x << 16);
        acc1 += w * __uint_as_float(g.x & 0xffff0000u);
        acc2 += w * __uint_as_float(g.y << 16);
        acc3 += w * __uint_as_float(g.y & 0xffff0000u);
    }
#undef EL
#undef EA

    acc0 += __shfl_xor(acc0, 32, 64);
    acc1 += __shfl_xor(acc1, 32, 64);
    acc2 += __shfl_xor(acc2, 32, 64);
    acc3 += __shfl_xor(acc3, 32, 64);

    if (half == 0) {
        float4 bv = *(const float4*)(bias + c * 4);
        acc0 = fmaxf(acc0 + bv.x, 0.f);
        acc1 = fmaxf(acc1 + bv.y, 0.f);
        acc2 = fmaxf(acc2 + bv.z, 0.f);
        acc3 = fmaxf(acc3 + bv.w, 0.f);
        if (OUTF32) {
            *(float4*)((float*)yv + (size_t)node * 128 + c * 4) =
                make_float4(acc0, acc1, acc2, acc3);
        } else {
            uint2 o;
            o.x = (uint)f2bf(acc0) | ((uint)f2bf(acc1) << 16);
            o.y = (uint)f2bf(acc2) | ((uint)f2bf(acc3) << 16);
            *(uint2*)((ushort*)yv + (size_t)node * 128 + c * 4) = o;
        }
    }
}

// ---------------- head: out[N][16] = emb[N][128] @ Wl[128][16] + bl ----------------
__global__ __launch_bounds__(256) void k_out(const float* __restrict__ emb,
                                             const float* __restrict__ Wl,
                                             const float* __restrict__ bl,
                                             float* __restrict__ out) {
    __shared__ float wl_s[128 * 16];
    __shared__ float es[16][129];
    int tid = threadIdx.x;
    int row0 = blockIdx.x * 16;
#pragma unroll
    for (int p = 0; p < 8; p++) wl_s[p * 256 + tid] = Wl[p * 256 + tid];
#pragma unroll
    for (int p = 0; p < 8; p++) {
        int idx = p * 256 + tid;
        int r = idx >> 7, c = idx & 127;
        int gr = row0 + r;
        es[r][c] = (gr < NN) ? emb[(size_t)gr * 128 + c] : 0.0f;
    }
    __syncthreads();
    int r = tid >> 4, o = tid & 15;
    float acc = bl[o];
#pragma unroll
    for (int k = 0; k < 128; k++) acc += es[r][k] * wl_s[k * 16 + o];
    int gr = row0 + r;
    if (gr < NN) out[(size_t)gr * 16 + o] = acc;
}

extern "C" void kernel_launch(void* const* d_in, const int* in_sizes, int n_in,
                              void* d_out, int out_size, void* d_ws, size_t ws_size,
                              hipStream_t stream) {
    const float* x  = (const float*)d_in[0];
    const int* ei   = (const int*)d_in[1];
    const float* W1 = (const float*)d_in[2];
    const float* b1 = (const float*)d_in[3];
    const float* W2 = (const float*)d_in[4];
    const float* b2 = (const float*)d_in[5];
    const float* Wl = (const float*)d_in[6];
    const float* bl = (const float*)d_in[7];
    const int* src = ei;
    const int* dst = ei + EE;

    float* outp = (float*)d_out;
    float* emb  = outp + (size_t)NN * OUTD;

    int2* ew    = (int2*)d_ws;
    int* pos    = (int*)(ew + EE);
    ushort* h_a = (ushort*)(pos + EE);
    ushort* h_b = h_a + (size_t)NN * 128;
    ushort* Wt1 = h_b + (size_t)NN * 128;
    ushort* Wt2 = Wt1 + 128 * 512;
    int* deg    = (int*)(Wt2 + 128 * 128);
    float* dis  = (float*)(deg + NN);
    float* dinv = dis + NN;
    int* incl   = (int*)(dinv + NN);
    int* rs     = incl + NN;
    int* bsum   = rs + NN + 8;
    int* boff   = bsum + 512;

    const int NB_N = (NN + 255) / 256;  // 391

    hipMemsetAsync(deg, 0, (size_t)NN * sizeof(int), stream);
    k_prep<<<320, 256, 0, stream>>>(W1, W2, Wt1, Wt2);
    // deg+pos (192 blocks) || gemm1 (x@W1 -> h_a bf16)
    k_mega1<<<DEG_BLKS + GEMM_BLKS, 256, 0, stream>>>(x, Wt1, h_a, dst, deg, pos);
    k_scan_local<<<NB_N, 256, 0, stream>>>(deg, incl, bsum);
    k_scan_bsum<<<1, 512, 0, stream>>>(bsum, boff, NB_N);
    k_scan_final<<<NB_N, 256, 0, stream>>>(incl, deg, boff, rs, dis, dinv);
    k_fill<<<2048, 256, 0, stream>>>(src, dst, pos, rs, dis, ew);

    k_agg<false><<<(NN + 3) / 4, 256, 0, stream>>>(h_a, rs, ew, dinv, b1, h_b);
    k_gemm2<<<GEMM_BLKS, 256, 0, stream>>>(h_b, Wt2, h_a);
    k_agg<true><<<(NN + 3) / 4, 256, 0, stream>>>(h_a, rs, ew, dinv, b2, emb);
    k_out<<<(NN + 15) / 16, 256, 0, stream>>>(emb, Wl, bl, outp);
}

// Round 18
// 332.642 us; speedup vs baseline: 1.2396x; 1.2396x over previous
//
#include <hip/hip_runtime.h>

#define NN 100000
#define EE 1600000
#define IND 512
#define HIDD 128
#define OUTD 16
#define DEG_BLKS 192
#define GEMM_BLKS 1563  // ceil(NN/64)

typedef __bf16 bf16x8 __attribute__((ext_vector_type(8)));
typedef float f32x4 __attribute__((ext_vector_type(4)));

__device__ __forceinline__ ushort f2bf(float f) {
    union { float f; uint u; } v; v.f = f;
    uint r = v.u + 0x7FFFu + ((v.u >> 16) & 1u);
    return (ushort)(r >> 16);
}

__device__ __forceinline__ uint pk2bf(float a, float b) {
    __bf16 x = (__bf16)a, y = (__bf16)b;
    ushort ux = *(ushort*)&x, uy = *(ushort*)&y;
    return (uint)ux | ((uint)uy << 16);
}

#define GLDS16(src, dst)                                              \
    __builtin_amdgcn_global_load_lds(                                 \
        (const __attribute__((address_space(1))) void*)(src),         \
        (__attribute__((address_space(3))) void*)(dst), 16, 0, 0)

// ---------------- W prep ----------------
__global__ void k_prep(const float* __restrict__ W1, const float* __restrict__ W2,
                       ushort* __restrict__ Wt1, ushort* __restrict__ Wt2) {
    int b = blockIdx.x, tid = threadIdx.x;
    if (b < 256) {
        int i = b * 256 + tid;
        int k = i >> 7, n = i & 127;
        Wt1[n * 512 + k] = f2bf(W1[i]);
    } else {
        int i = (b - 256) * 256 + tid;
        int k = i >> 7, n = i & 127;
        Wt2[n * 128 + k] = f2bf(W2[i]);
    }
}

// ---------------- scan (3 phases; norm fused into final) ----------------
__global__ void k_scan_local(const int* __restrict__ deg, int* __restrict__ incl,
                             int* __restrict__ bsum) {
    __shared__ int s[256];
    int tid = threadIdx.x;
    int i = blockIdx.x * 256 + tid;
    int v = (i < NN) ? deg[i] : 0;
    s[tid] = v;
    __syncthreads();
    for (int off = 1; off < 256; off <<= 1) {
        int t = (tid >= off) ? s[tid - off] : 0;
        __syncthreads();
        s[tid] += t;
        __syncthreads();
    }
    if (i < NN) incl[i] = s[tid];
    if (tid == 255) bsum[blockIdx.x] = s[255];
}

__global__ void k_scan_bsum(const int* __restrict__ bsum, int* __restrict__ boff, int n) {
    __shared__ int s[512];
    int tid = threadIdx.x;
    int v = (tid < n) ? bsum[tid] : 0;
    s[tid] = v;
    __syncthreads();
    for (int off = 1; off < 512; off <<= 1) {
        int t = (tid >= off) ? s[tid - off] : 0;
        __syncthreads();
        s[tid] += t;
        __syncthreads();
    }
    if (tid < n) boff[tid] = s[tid] - v;  // exclusive
}

__global__ void k_scan_final(const int* __restrict__ incl, const int* __restrict__ deg,
                             const int* __restrict__ boff, int* __restrict__ rs,
                             float* __restrict__ dis, float* __restrict__ dinv) {
    int i = blockIdx.x * 256 + threadIdx.x;
    if (i < NN) {
        int d = deg[i];
        int v = incl[i] + boff[i >> 8];
        rs[i] = v - d;
        if (i == NN - 1) rs[NN] = v;
        float df = (float)(d + 1);
        dis[i] = rsqrtf(df);
        dinv[i] = 1.0f / df;
    }
}

// ---------------- CSR fill: atomic-free ----------------
__global__ void k_fill(const int* __restrict__ src, const int* __restrict__ dst,
                       const int* __restrict__ pos, const int* __restrict__ rs,
                       const float* __restrict__ dis, int2* __restrict__ ew) {
    int i = blockIdx.x * blockDim.x + threadIdx.x;
    int stride = gridDim.x * blockDim.x;
    for (; i < EE; i += stride) {
        int d = dst[i];
        int s = src[i];
        ew[rs[d] + pos[i]] = make_int2(s, __float_as_int(dis[s] * dis[d]));
    }
}

// ---------------- bf16 MFMA GEMM body (R9/R16 structure: DMA dbuf, counted vmcnt) ----------------
template <int K, bool AFP32>
__device__ __forceinline__ void gemm_body(const void* __restrict__ Ap,
                                          const ushort* __restrict__ Wt,
                                          ushort* __restrict__ C, int M, int blk) {
    constexpr int NT = K / 32;
    constexpr int ABYTES = AFP32 ? 64 * 32 * 4 : 64 * 32 * 2;
    constexpr int WBYTES = 128 * 32 * 2;
    __shared__ char smem[2 * (ABYTES + WBYTES)];

    int tid = threadIdx.x;
    int row0 = blk * 64;
    int wid = tid >> 6, lane = tid & 63;
    int wm = wid * 16;
    int lm = lane & 15, lk8 = (lane >> 4) * 8;

    const float* Af = (const float*)Ap;
    const ushort* Ab16 = (const ushort*)Ap;

    f32x4 acc[8];
#pragma unroll
    for (int q = 0; q < 8; q++) acc[q] = (f32x4){0.f, 0.f, 0.f, 0.f};

    auto stage = [&](int bi, int k0) {
        char* Abase = smem + bi * ABYTES;
        char* Wbase = smem + 2 * ABYTES + bi * WBYTES;
        if (AFP32) {
#pragma unroll
            for (int j = 0; j < 2; j++) {
                int c = wid * 2 + j;
                int rp = c * 8 + (lane >> 3);
                int sl = (lane & 7) ^ (rp & 7);
                int gr2 = row0 + rp; if (gr2 >= M) gr2 = M - 1;
                GLDS16(Af + (size_t)gr2 * K + k0 + sl * 4, Abase + c * 1024);
            }
        } else {
            int c = wid;
            int rp = c * 16 + (lane >> 2);
            int sl = (lane & 3) ^ (rp & 3);
            int gr2 = row0 + rp; if (gr2 >= M) gr2 = M - 1;
            GLDS16(Ab16 + (size_t)gr2 * K + k0 + sl * 8, Abase + c * 1024);
        }
#pragma unroll
        for (int j = 0; j < 2; j++) {
            int c = wid * 2 + j;
            int rp = c * 16 + (lane >> 2);
            int sl = (lane & 3) ^ (rp & 3);
            GLDS16(Wt + (size_t)rp * K + k0 + sl * 8, Wbase + c * 1024);
        }
    };

    stage(0, 0);

    int cur = 0;
    for (int t = 0; t < NT; t++) {
        if (t + 1 < NT) {
            stage((t + 1) & 1, (t + 1) * 32);
            if (AFP32) asm volatile("s_waitcnt vmcnt(4)" ::: "memory");
            else       asm volatile("s_waitcnt vmcnt(3)" ::: "memory");
        } else {
            asm volatile("s_waitcnt vmcnt(0)" ::: "memory");
        }
        __builtin_amdgcn_s_barrier();

        char* Abase = smem + cur * ABYTES;
        char* Wbase = smem + 2 * ABYTES + cur * WBYTES;
        bf16x8 xf, wf[8];
        if (AFP32) {
            int r_ = wm + lm;
            int s0 = lk8 >> 2;
            f32x4 a0 = *(const f32x4*)(Abase + r_ * 128 + (((s0)     ^ (r_ & 7)) << 4));
            f32x4 a1 = *(const f32x4*)(Abase + r_ * 128 + (((s0 + 1) ^ (r_ & 7)) << 4));
            uint4 u;
            u.x = pk2bf(a0[0], a0[1]);
            u.y = pk2bf(a0[2], a0[3]);
            u.z = pk2bf(a1[0], a1[1]);
            u.w = pk2bf(a1[2], a1[3]);
            xf = *(bf16x8*)&u;
        } else {
            int r_ = wm + lm;
            int s = lk8 >> 3;
            uint4 u = *(const uint4*)(Abase + r_ * 64 + ((s ^ (r_ & 3)) << 4));
            xf = *(bf16x8*)&u;
        }
#pragma unroll
        for (int q = 0; q < 8; q++) {
            int n_ = q * 16 + lm;
            int s = lk8 >> 3;
            uint4 u = *(const uint4*)(Wbase + n_ * 64 + ((s ^ (n_ & 3)) << 4));
            wf[q] = *(bf16x8*)&u;
        }
#pragma unroll
        for (int q = 0; q < 8; q++)
            acc[q] = __builtin_amdgcn_mfma_f32_16x16x32_bf16(wf[q], xf, acc[q], 0, 0, 0);

        asm volatile("" ::: "memory");
        __builtin_amdgcn_s_barrier();
        cur ^= 1;
    }

    int cn4 = (lane >> 4) * 4;
    int m = row0 + wm + lm;
    if (m < M) {
#pragma unroll
        for (int q = 0; q < 8; q++) {
            int n = q * 16 + cn4;
            uint2 o;
            o.x = (uint)f2bf(acc[q][0]) | ((uint)f2bf(acc[q][1]) << 16);
            o.y = (uint)f2bf(acc[q][2]) | ((uint)f2bf(acc[q][3]) << 16);
            *(uint2*)(C + (size_t)m * 128 + n) = o;
        }
    }
}

// mega1: blocks [0,DEG_BLKS) do deg+pos (atomicAdd returns slot); rest do GEMM1.
__global__ __launch_bounds__(256, 5) void k_mega1(const float* __restrict__ x,
                                                  const ushort* __restrict__ Wt1,
                                                  ushort* __restrict__ C,
                                                  const int* __restrict__ dst,
                                                  int* __restrict__ deg,
                                                  int* __restrict__ pos) {
    if (blockIdx.x < DEG_BLKS) {
        int i = blockIdx.x * 256 + threadIdx.x;
        int stride = DEG_BLKS * 256;
        for (; i < EE; i += stride) pos[i] = atomicAdd(&deg[dst[i]], 1);
    } else {
        gemm_body<IND, true>(x, Wt1, C, NN, blockIdx.x - DEG_BLKS);
    }
}

__global__ __launch_bounds__(256, 6) void k_gemm2(const ushort* __restrict__ A,
                                                  const ushort* __restrict__ Wt,
                                                  ushort* __restrict__ C) {
    gemm_body<HIDD, false>(A, Wt, C, NN, blockIdx.x);
}

// ---------------- aggregation: half-wave per node, quarter-wave edge streams ----------------
// 2 nodes per wave (8 per block). Within a 32-lane half: quarter q=0 handles
// even edges, q=1 odd edges; 16 lanes x uint4 (8 dims) cover the 128-dim row.
// 8-pair main loop = 16 edges in flight per node = 32 rows per wave.
template <bool OUTF32>
__global__ __launch_bounds__(256) void k_agg(const ushort* __restrict__ h,
                                             const int* __restrict__ rs,
                                             const int2* __restrict__ ew,
                                             const float* __restrict__ dinv,
                                             const float* __restrict__ bias,
                                             void* __restrict__ yv) {
    int tid = threadIdx.x;
    int node = blockIdx.x * 8 + (tid >> 5);
    if (node >= NN) return;
    int hl = tid & 31;
    int q = hl >> 4;   // quarter within half: even/odd edge stream
    int c = hl & 15;   // 16 lanes x 8 dims = 128
    const uint4* h128 = (const uint4*)h;  // row stride 16 (16B units)

    float a0 = 0.f, a1 = 0.f, a2 = 0.f, a3 = 0.f, a4 = 0.f, a5 = 0.f, a6 = 0.f, a7 = 0.f;
    if (q == 0) {  // self-loop term on even-quarter only
        float dv = dinv[node];
        uint4 sv = h128[(size_t)node * 16 + c];
        a0 = __uint_as_float(sv.x << 16) * dv; a1 = __uint_as_float(sv.x & 0xffff0000u) * dv;
        a2 = __uint_as_float(sv.y << 16) * dv; a3 = __uint_as_float(sv.y & 0xffff0000u) * dv;
        a4 = __uint_as_float(sv.z << 16) * dv; a5 = __uint_as_float(sv.z & 0xffff0000u) * dv;
        a6 = __uint_as_float(sv.w << 16) * dv; a7 = __uint_as_float(sv.w & 0xffff0000u) * dv;
    }

    int e = rs[node], e1 = rs[node + 1];

#define EL(i) int2 p##i = ew[e + 2 * i + q]; \
              uint4 g##i = h128[(size_t)(uint)p##i.x * 16 + c];
#define EA(i) { float w##i = __int_as_float(p##i.y); \
    a0 += w##i * __uint_as_float(g##i.x << 16); \
    a1 += w##i * __uint_as_float(g##i.x & 0xffff0000u); \
    a2 += w##i * __uint_as_float(g##i.y << 16); \
    a3 += w##i * __uint_as_float(g##i.y & 0xffff0000u); \
    a4 += w##i * __uint_as_float(g##i.z << 16); \
    a5 += w##i * __uint_as_float(g##i.z & 0xffff0000u); \
    a6 += w##i * __uint_as_float(g##i.w << 16); \
    a7 += w##i * __uint_as_float(g##i.w & 0xffff0000u); }

    for (; e + 16 <= e1; e += 16) {  // 8 pairs = 16 edges in flight per node
        EL(0) EL(1) EL(2) EL(3) EL(4) EL(5) EL(6) EL(7)
        EA(0) EA(1) EA(2) EA(3) EA(4) EA(5) EA(6) EA(7)
    }
    for (; e + 4 <= e1; e += 4) {    // 2 pairs
        EL(0) EL(1)
        EA(0) EA(1)
    }
    if (e + 2 <= e1) {               // 1 pair
        EL(0)
        EA(0)
        e += 2;
    }
    if (e < e1 && q == 0) {          // final odd edge
        int2 p = ew[e];
        uint4 g = h128[(size_t)(uint)p.x * 16 + c];
        float w = __int_as_float(p.y);
        a0 += w * __uint_as_float(g.x << 16); a1 += w * __uint_as_float(g.x & 0xffff0000u);
        a2 += w * __uint_as_float(g.y << 16); a3 += w * __uint_as_float(g.y & 0xffff0000u);
        a4 += w * __uint_as_float(g.z << 16); a5 += w * __uint_as_float(g.z & 0xffff0000u);
        a6 += w * __uint_as_float(g.w << 16); a7 += w * __uint_as_float(g.w & 0xffff0000u);
    }
#undef EL
#undef EA

    // merge quarters (lane +-16 within each half)
    a0 += __shfl_xor(a0, 16, 64); a1 += __shfl_xor(a1, 16, 64);
    a2 += __shfl_xor(a2, 16, 64); a3 += __shfl_xor(a3, 16, 64);
    a4 += __shfl_xor(a4, 16, 64); a5 += __shfl_xor(a5, 16, 64);
    a6 += __shfl_xor(a6, 16, 64); a7 += __shfl_xor(a7, 16, 64);

    if (q == 0) {
        float4 b0 = *(const float4*)(bias + c * 8);
        float4 b1 = *(const float4*)(bias + c * 8 + 4);
        a0 = fmaxf(a0 + b0.x, 0.f); a1 = fmaxf(a1 + b0.y, 0.f);
        a2 = fmaxf(a2 + b0.z, 0.f); a3 = fmaxf(a3 + b0.w, 0.f);
        a4 = fmaxf(a4 + b1.x, 0.f); a5 = fmaxf(a5 + b1.y, 0.f);
        a6 = fmaxf(a6 + b1.z, 0.f); a7 = fmaxf(a7 + b1.w, 0.f);
        if (OUTF32) {
            float* y = (float*)yv + (size_t)node * 128 + c * 8;
            *(float4*)(y)     = make_float4(a0, a1, a2, a3);
            *(float4*)(y + 4) = make_float4(a4, a5, a6, a7);
        } else {
            uint4 o;
            o.x = (uint)f2bf(a0) | ((uint)f2bf(a1) << 16);
            o.y = (uint)f2bf(a2) | ((uint)f2bf(a3) << 16);
            o.z = (uint)f2bf(a4) | ((uint)f2bf(a5) << 16);
            o.w = (uint)f2bf(a6) | ((uint)f2bf(a7) << 16);
            *(uint4*)((ushort*)yv + (size_t)node * 128 + c * 8) = o;
        }
    }
}

// ---------------- head: out[N][16] = emb[N][128] @ Wl[128][16] + bl ----------------
__global__ __launch_bounds__(256) void k_out(const float* __restrict__ emb,
                                             const float* __restrict__ Wl,
                                             const float* __restrict__ bl,
                                             float* __restrict__ out) {
    __shared__ float wl_s[128 * 16];
    __shared__ float es[16][129];
    int tid = threadIdx.x;
    int row0 = blockIdx.x * 16;
#pragma unroll
    for (int p = 0; p < 8; p++) wl_s[p * 256 + tid] = Wl[p * 256 + tid];
#pragma unroll
    for (int p = 0; p < 8; p++) {
        int idx = p * 256 + tid;
        int r = idx >> 7, c = idx & 127;
        int gr = row0 + r;
        es[r][c] = (gr < NN) ? emb[(size_t)gr * 128 + c] : 0.0f;
    }
    __syncthreads();
    int r = tid >> 4, o = tid & 15;
    float acc = bl[o];
#pragma unroll
    for (int k = 0; k < 128; k++) acc += es[r][k] * wl_s[k * 16 + o];
    int gr = row0 + r;
    if (gr < NN) out[(size_t)gr * 16 + o] = acc;
}

extern "C" void kernel_launch(void* const* d_in, const int* in_sizes, int n_in,
                              void* d_out, int out_size, void* d_ws, size_t ws_size,
                              hipStream_t stream) {
    const float* x  = (const float*)d_in[0];
    const int* ei   = (const int*)d_in[1];
    const float* W1 = (const float*)d_in[2];
    const float* b1 = (const float*)d_in[3];
    const float* W2 = (const float*)d_in[4];
    const float* b2 = (const float*)d_in[5];
    const float* Wl = (const float*)d_in[6];
    const float* bl = (const float*)d_in[7];
    const int* src = ei;
    const int* dst = ei + EE;

    float* outp = (float*)d_out;
    float* emb  = outp + (size_t)NN * OUTD;

    int2* ew    = (int2*)d_ws;
    int* pos    = (int*)(ew + EE);
    ushort* h_a = (ushort*)(pos + EE);
    ushort* h_b = h_a + (size_t)NN * 128;
    ushort* Wt1 = h_b + (size_t)NN * 128;
    ushort* Wt2 = Wt1 + 128 * 512;
    int* deg    = (int*)(Wt2 + 128 * 128);
    float* dis  = (float*)(deg + NN);
    float* dinv = dis + NN;
    int* incl   = (int*)(dinv + NN);
    int* rs     = incl + NN;
    int* bsum   = rs + NN + 8;
    int* boff   = bsum + 512;

    const int NB_N = (NN + 255) / 256;  // 391

    hipMemsetAsync(deg, 0, (size_t)NN * sizeof(int), stream);
    k_prep<<<320, 256, 0, stream>>>(W1, W2, Wt1, Wt2);
    // deg+pos (192 blocks) || gemm1 (x@W1 -> h_a bf16)
    k_mega1<<<DEG_BLKS + GEMM_BLKS, 256, 0, stream>>>(x, Wt1, h_a, dst, deg, pos);
    k_scan_local<<<NB_N, 256, 0, stream>>>(deg, incl, bsum);
    k_scan_bsum<<<1, 512, 0, stream>>>(bsum, boff, NB_N);
    k_scan_final<<<NB_N, 256, 0, stream>>>(incl, deg, boff, rs, dis, dinv);
    k_fill<<<2048, 256, 0, stream>>>(src, dst, pos, rs, dis, ew);

    k_agg<false><<<(NN + 7) / 8, 256, 0, stream>>>(h_a, rs, ew, dinv, b1, h_b);
    k_gemm2<<<GEMM_BLKS, 256, 0, stream>>>(h_b, Wt2, h_a);
    k_agg<true><<<(NN + 7) / 8, 256, 0, stream>>>(h_a, rs, ew, dinv, b2, emb);
    k_out<<<(NN + 15) / 16, 256, 0, stream>>>(emb, Wl, bl, outp);
}

// Round 19
// 330.685 us; speedup vs baseline: 1.2469x; 1.0059x over previous
//
#include <hip/hip_runtime.h>

#define NN 100000
#define EE 1600000
#define IND 512
#define HIDD 128
#define OUTD 16
#define DEG_BLKS 192
#define GEMM_BLKS 1563  // ceil(NN/64)

typedef __bf16 bf16x8 __attribute__((ext_vector_type(8)));
typedef float f32x4 __attribute__((ext_vector_type(4)));

__device__ __forceinline__ ushort f2bf(float f) {
    union { float f; uint u; } v; v.f = f;
    uint r = v.u + 0x7FFFu + ((v.u >> 16) & 1u);
    return (ushort)(r >> 16);
}

__device__ __forceinline__ uint pk2bf(float a, float b) {
    __bf16 x = (__bf16)a, y = (__bf16)b;
    ushort ux = *(ushort*)&x, uy = *(ushort*)&y;
    return (uint)ux | ((uint)uy << 16);
}

#define GLDS16(src, dst)                                              \
    __builtin_amdgcn_global_load_lds(                                 \
        (const __attribute__((address_space(1))) void*)(src),         \
        (__attribute__((address_space(3))) void*)(dst), 16, 0, 0)

// ---------------- W prep + deg zeroing (memset folded in) ----------------
__global__ void k_prep(const float* __restrict__ W1, const float* __restrict__ W2,
                       ushort* __restrict__ Wt1, ushort* __restrict__ Wt2,
                       int* __restrict__ deg) {
    int b = blockIdx.x, tid = threadIdx.x;
    if (b < 256) {
        int i = b * 256 + tid;
        int k = i >> 7, n = i & 127;
        Wt1[n * 512 + k] = f2bf(W1[i]);
    } else if (b < 320) {
        int i = (b - 256) * 256 + tid;
        int k = i >> 7, n = i & 127;
        Wt2[n * 128 + k] = f2bf(W2[i]);
    } else {
        int i = (b - 320) * 256 + tid;
        if (i < NN) deg[i] = 0;
    }
}

// ---------------- scan phase 1 ----------------
__global__ void k_scan_local(const int* __restrict__ deg, int* __restrict__ incl,
                             int* __restrict__ bsum) {
    __shared__ int s[256];
    int tid = threadIdx.x;
    int i = blockIdx.x * 256 + tid;
    int v = (i < NN) ? deg[i] : 0;
    s[tid] = v;
    __syncthreads();
    for (int off = 1; off < 256; off <<= 1) {
        int t = (tid >= off) ? s[tid - off] : 0;
        __syncthreads();
        s[tid] += t;
        __syncthreads();
    }
    if (i < NN) incl[i] = s[tid];
    if (tid == 255) bsum[blockIdx.x] = s[255];
}

// ---------------- scan phase 2 (bsum-prefix computed per block; norm fused) ----------------
__global__ void k_scan_final(const int* __restrict__ incl, const int* __restrict__ deg,
                             const int* __restrict__ bsum, int* __restrict__ rs,
                             float* __restrict__ dis, float* __restrict__ dinv) {
    __shared__ int red[256];
    int tid = threadIdx.x;
    int blk = blockIdx.x;
    int part = 0;
    for (int j = tid; j < blk; j += 256) part += bsum[j];
    red[tid] = part;
    __syncthreads();
    for (int off = 128; off > 0; off >>= 1) {
        if (tid < off) red[tid] += red[tid + off];
        __syncthreads();
    }
    int boff = red[0];  // exclusive block prefix

    int i = blk * 256 + tid;
    if (i < NN) {
        int d = deg[i];
        int v = incl[i] + boff;
        rs[i] = v - d;
        if (i == NN - 1) rs[NN] = v;
        float df = (float)(d + 1);
        dis[i] = rsqrtf(df);
        dinv[i] = 1.0f / df;
    }
}

// ---------------- CSR fill: atomic-free ----------------
__global__ void k_fill(const int* __restrict__ src, const int* __restrict__ dst,
                       const int* __restrict__ pos, const int* __restrict__ rs,
                       const float* __restrict__ dis, int2* __restrict__ ew) {
    int i = blockIdx.x * blockDim.x + threadIdx.x;
    int stride = gridDim.x * blockDim.x;
    for (; i < EE; i += stride) {
        int d = dst[i];
        int s = src[i];
        ew[rs[d] + pos[i]] = make_int2(s, __float_as_int(dis[s] * dis[d]));
    }
}

// ---------------- bf16 MFMA GEMM body (R9/R16 structure: DMA dbuf, counted vmcnt) ----------------
template <int K, bool AFP32>
__device__ __forceinline__ void gemm_body(const void* __restrict__ Ap,
                                          const ushort* __restrict__ Wt,
                                          ushort* __restrict__ C, int M, int blk) {
    constexpr int NT = K / 32;
    constexpr int ABYTES = AFP32 ? 64 * 32 * 4 : 64 * 32 * 2;
    constexpr int WBYTES = 128 * 32 * 2;
    __shared__ char smem[2 * (ABYTES + WBYTES)];

    int tid = threadIdx.x;
    int row0 = blk * 64;
    int wid = tid >> 6, lane = tid & 63;
    int wm = wid * 16;
    int lm = lane & 15, lk8 = (lane >> 4) * 8;

    const float* Af = (const float*)Ap;
    const ushort* Ab16 = (const ushort*)Ap;

    f32x4 acc[8];
#pragma unroll
    for (int q = 0; q < 8; q++) acc[q] = (f32x4){0.f, 0.f, 0.f, 0.f};

    auto stage = [&](int bi, int k0) {
        char* Abase = smem + bi * ABYTES;
        char* Wbase = smem + 2 * ABYTES + bi * WBYTES;
        if (AFP32) {
#pragma unroll
            for (int j = 0; j < 2; j++) {
                int c = wid * 2 + j;
                int rp = c * 8 + (lane >> 3);
                int sl = (lane & 7) ^ (rp & 7);
                int gr2 = row0 + rp; if (gr2 >= M) gr2 = M - 1;
                GLDS16(Af + (size_t)gr2 * K + k0 + sl * 4, Abase + c * 1024);
            }
        } else {
            int c = wid;
            int rp = c * 16 + (lane >> 2);
            int sl = (lane & 3) ^ (rp & 3);
            int gr2 = row0 + rp; if (gr2 >= M) gr2 = M - 1;
            GLDS16(Ab16 + (size_t)gr2 * K + k0 + sl * 8, Abase + c * 1024);
        }
#pragma unroll
        for (int j = 0; j < 2; j++) {
            int c = wid * 2 + j;
            int rp = c * 16 + (lane >> 2);
            int sl = (lane & 3) ^ (rp & 3);
            GLDS16(Wt + (size_t)rp * K + k0 + sl * 8, Wbase + c * 1024);
        }
    };

    stage(0, 0);

    int cur = 0;
    for (int t = 0; t < NT; t++) {
        if (t + 1 < NT) {
            stage((t + 1) & 1, (t + 1) * 32);
            if (AFP32) asm volatile("s_waitcnt vmcnt(4)" ::: "memory");
            else       asm volatile("s_waitcnt vmcnt(3)" ::: "memory");
        } else {
            asm volatile("s_waitcnt vmcnt(0)" ::: "memory");
        }
        __builtin_amdgcn_s_barrier();

        char* Abase = smem + cur * ABYTES;
        char* Wbase = smem + 2 * ABYTES + cur * WBYTES;
        bf16x8 xf, wf[8];
        if (AFP32) {
            int r_ = wm + lm;
            int s0 = lk8 >> 2;
            f32x4 a0 = *(const f32x4*)(Abase + r_ * 128 + (((s0)     ^ (r_ & 7)) << 4));
            f32x4 a1 = *(const f32x4*)(Abase + r_ * 128 + (((s0 + 1) ^ (r_ & 7)) << 4));
            uint4 u;
            u.x = pk2bf(a0[0], a0[1]);
            u.y = pk2bf(a0[2], a0[3]);
            u.z = pk2bf(a1[0], a1[1]);
            u.w = pk2bf(a1[2], a1[3]);
            xf = *(bf16x8*)&u;
        } else {
            int r_ = wm + lm;
            int s = lk8 >> 3;
            uint4 u = *(const uint4*)(Abase + r_ * 64 + ((s ^ (r_ & 3)) << 4));
            xf = *(bf16x8*)&u;
        }
#pragma unroll
        for (int q = 0; q < 8; q++) {
            int n_ = q * 16 + lm;
            int s = lk8 >> 3;
            uint4 u = *(const uint4*)(Wbase + n_ * 64 + ((s ^ (n_ & 3)) << 4));
            wf[q] = *(bf16x8*)&u;
        }
#pragma unroll
        for (int q = 0; q < 8; q++)
            acc[q] = __builtin_amdgcn_mfma_f32_16x16x32_bf16(wf[q], xf, acc[q], 0, 0, 0);

        asm volatile("" ::: "memory");
        __builtin_amdgcn_s_barrier();
        cur ^= 1;
    }

    int cn4 = (lane >> 4) * 4;
    int m = row0 + wm + lm;
    if (m < M) {
#pragma unroll
        for (int q = 0; q < 8; q++) {
            int n = q * 16 + cn4;
            uint2 o;
            o.x = (uint)f2bf(acc[q][0]) | ((uint)f2bf(acc[q][1]) << 16);
            o.y = (uint)f2bf(acc[q][2]) | ((uint)f2bf(acc[q][3]) << 16);
            *(uint2*)(C + (size_t)m * 128 + n) = o;
        }
    }
}

// mega1: blocks [0,DEG_BLKS) do deg+pos (atomicAdd returns slot); rest do GEMM1.
__global__ __launch_bounds__(256, 5) void k_mega1(const float* __restrict__ x,
                                                  const ushort* __restrict__ Wt1,
                                                  ushort* __restrict__ C,
                                                  const int* __restrict__ dst,
                                                  int* __restrict__ deg,
                                                  int* __restrict__ pos) {
    if (blockIdx.x < DEG_BLKS) {
        int i = blockIdx.x * 256 + threadIdx.x;
        int stride = DEG_BLKS * 256;
        for (; i < EE; i += stride) pos[i] = atomicAdd(&deg[dst[i]], 1);
    } else {
        gemm_body<IND, true>(x, Wt1, C, NN, blockIdx.x - DEG_BLKS);
    }
}

__global__ __launch_bounds__(256, 6) void k_gemm2(const ushort* __restrict__ A,
                                                  const ushort* __restrict__ Wt,
                                                  ushort* __restrict__ C) {
    gemm_body<HIDD, false>(A, Wt, C, NN, blockIdx.x);
}

// ---------------- aggregation: half-wave per node, quarter-wave edge streams ----------------
template <bool OUTF32>
__global__ __launch_bounds__(256) void k_agg(const ushort* __restrict__ h,
                                             const int* __restrict__ rs,
                                             const int2* __restrict__ ew,
                                             const float* __restrict__ dinv,
                                             const float* __restrict__ bias,
                                             void* __restrict__ yv) {
    int tid = threadIdx.x;
    int node = blockIdx.x * 8 + (tid >> 5);
    if (node >= NN) return;
    int hl = tid & 31;
    int q = hl >> 4;
    int c = hl & 15;
    const uint4* h128 = (const uint4*)h;

    float a0 = 0.f, a1 = 0.f, a2 = 0.f, a3 = 0.f, a4 = 0.f, a5 = 0.f, a6 = 0.f, a7 = 0.f;
    if (q == 0) {
        float dv = dinv[node];
        uint4 sv = h128[(size_t)node * 16 + c];
        a0 = __uint_as_float(sv.x << 16) * dv; a1 = __uint_as_float(sv.x & 0xffff0000u) * dv;
        a2 = __uint_as_float(sv.y << 16) * dv; a3 = __uint_as_float(sv.y & 0xffff0000u) * dv;
        a4 = __uint_as_float(sv.z << 16) * dv; a5 = __uint_as_float(sv.z & 0xffff0000u) * dv;
        a6 = __uint_as_float(sv.w << 16) * dv; a7 = __uint_as_float(sv.w & 0xffff0000u) * dv;
    }

    int e = rs[node], e1 = rs[node + 1];

#define EL(i) int2 p##i = ew[e + 2 * i + q]; \
              uint4 g##i = h128[(size_t)(uint)p##i.x * 16 + c];
#define EA(i) { float w##i = __int_as_float(p##i.y); \
    a0 += w##i * __uint_as_float(g##i.x << 16); \
    a1 += w##i * __uint_as_float(g##i.x & 0xffff0000u); \
    a2 += w##i * __uint_as_float(g##i.y << 16); \
    a3 += w##i * __uint_as_float(g##i.y & 0xffff0000u); \
    a4 += w##i * __uint_as_float(g##i.z << 16); \
    a5 += w##i * __uint_as_float(g##i.z & 0xffff0000u); \
    a6 += w##i * __uint_as_float(g##i.w << 16); \
    a7 += w##i * __uint_as_float(g##i.w & 0xffff0000u); }

    for (; e + 16 <= e1; e += 16) {
        EL(0) EL(1) EL(2) EL(3) EL(4) EL(5) EL(6) EL(7)
        EA(0) EA(1) EA(2) EA(3) EA(4) EA(5) EA(6) EA(7)
    }
    for (; e + 4 <= e1; e += 4) {
        EL(0) EL(1)
        EA(0) EA(1)
    }
    if (e + 2 <= e1) {
        EL(0)
        EA(0)
        e += 2;
    }
    if (e < e1 && q == 0) {
        int2 p = ew[e];
        uint4 g = h128[(size_t)(uint)p.x * 16 + c];
        float w = __int_as_float(p.y);
        a0 += w * __uint_as_float(g.x << 16); a1 += w * __uint_as_float(g.x & 0xffff0000u);
        a2 += w * __uint_as_float(g.y << 16); a3 += w * __uint_as_float(g.y & 0xffff0000u);
        a4 += w * __uint_as_float(g.z << 16); a5 += w * __uint_as_float(g.z & 0xffff0000u);
        a6 += w * __uint_as_float(g.w << 16); a7 += w * __uint_as_float(g.w & 0xffff0000u);
    }
#undef EL
#undef EA

    a0 += __shfl_xor(a0, 16, 64); a1 += __shfl_xor(a1, 16, 64);
    a2 += __shfl_xor(a2, 16, 64); a3 += __shfl_xor(a3, 16, 64);
    a4 += __shfl_xor(a4, 16, 64); a5 += __shfl_xor(a5, 16, 64);
    a6 += __shfl_xor(a6, 16, 64); a7 += __shfl_xor(a7, 16, 64);

    if (q == 0) {
        float4 b0 = *(const float4*)(bias + c * 8);
        float4 b1 = *(const float4*)(bias + c * 8 + 4);
        a0 = fmaxf(a0 + b0.x, 0.f); a1 = fmaxf(a1 + b0.y, 0.f);
        a2 = fmaxf(a2 + b0.z, 0.f); a3 = fmaxf(a3 + b0.w, 0.f);
        a4 = fmaxf(a4 + b1.x, 0.f); a5 = fmaxf(a5 + b1.y, 0.f);
        a6 = fmaxf(a6 + b1.z, 0.f); a7 = fmaxf(a7 + b1.w, 0.f);
        if (OUTF32) {
            float* y = (float*)yv + (size_t)node * 128 + c * 8;
            *(float4*)(y)     = make_float4(a0, a1, a2, a3);
            *(float4*)(y + 4) = make_float4(a4, a5, a6, a7);
        } else {
            uint4 o;
            o.x = (uint)f2bf(a0) | ((uint)f2bf(a1) << 16);
            o.y = (uint)f2bf(a2) | ((uint)f2bf(a3) << 16);
            o.z = (uint)f2bf(a4) | ((uint)f2bf(a5) << 16);
            o.w = (uint)f2bf(a6) | ((uint)f2bf(a7) << 16);
            *(uint4*)((ushort*)yv + (size_t)node * 128 + c * 8) = o;
        }
    }
}

// ---------------- head: out[N][16] = emb[N][128] @ Wl[128][16] + bl ----------------
__global__ __launch_bounds__(256) void k_out(const float* __restrict__ emb,
                                             const float* __restrict__ Wl,
                                             const float* __restrict__ bl,
                                             float* __restrict__ out) {
    __shared__ float wl_s[128 * 16];
    __shared__ float es[16][129];
    int tid = threadIdx.x;
    int row0 = blockIdx.x * 16;
#pragma unroll
    for (int p = 0; p < 8; p++) wl_s[p * 256 + tid] = Wl[p * 256 + tid];
#pragma unroll
    for (int p = 0; p < 8; p++) {
        int idx = p * 256 + tid;
        int r = idx >> 7, c = idx & 127;
        int gr = row0 + r;
        es[r][c] = (gr < NN) ? emb[(size_t)gr * 128 + c] : 0.0f;
    }
    __syncthreads();
    int r = tid >> 4, o = tid & 15;
    float acc = bl[o];
#pragma unroll
    for (int k = 0; k < 128; k++) acc += es[r][k] * wl_s[k * 16 + o];
    int gr = row0 + r;
    if (gr < NN) out[(size_t)gr * 16 + o] = acc;
}

extern "C" void kernel_launch(void* const* d_in, const int* in_sizes, int n_in,
                              void* d_out, int out_size, void* d_ws, size_t ws_size,
                              hipStream_t stream) {
    const float* x  = (const float*)d_in[0];
    const int* ei   = (const int*)d_in[1];
    const float* W1 = (const float*)d_in[2];
    const float* b1 = (const float*)d_in[3];
    const float* W2 = (const float*)d_in[4];
    const float* b2 = (const float*)d_in[5];
    const float* Wl = (const float*)d_in[6];
    const float* bl = (const float*)d_in[7];
    const int* src = ei;
    const int* dst = ei + EE;

    float* outp = (float*)d_out;
    float* emb  = outp + (size_t)NN * OUTD;

    int2* ew    = (int2*)d_ws;
    int* pos    = (int*)(ew + EE);
    ushort* h_a = (ushort*)(pos + EE);
    ushort* h_b = h_a + (size_t)NN * 128;
    ushort* Wt1 = h_b + (size_t)NN * 128;
    ushort* Wt2 = Wt1 + 128 * 512;
    int* deg    = (int*)(Wt2 + 128 * 128);
    float* dis  = (float*)(deg + NN);
    float* dinv = dis + NN;
    int* incl   = (int*)(dinv + NN);
    int* rs     = incl + NN;
    int* bsum   = rs + NN + 8;

    const int NB_N = (NN + 255) / 256;  // 391

    // prep (W cvt + deg zeroing)
    k_prep<<<320 + NB_N, 256, 0, stream>>>(W1, W2, Wt1, Wt2, deg);
    // deg+pos (192 blocks) || gemm1 (x@W1 -> h_a bf16)
    k_mega1<<<DEG_BLKS + GEMM_BLKS, 256, 0, stream>>>(x, Wt1, h_a, dst, deg, pos);
    k_scan_local<<<NB_N, 256, 0, stream>>>(deg, incl, bsum);
    k_scan_final<<<NB_N, 256, 0, stream>>>(incl, deg, bsum, rs, dis, dinv);
    k_fill<<<2048, 256, 0, stream>>>(src, dst, pos, rs, dis, ew);

    k_agg<false><<<(NN + 7) / 8, 256, 0, stream>>>(h_a, rs, ew, dinv, b1, h_b);
    k_gemm2<<<GEMM_BLKS, 256, 0, stream>>>(h_b, Wt2, h_a);
    k_agg<true><<<(NN + 7) / 8, 256, 0, stream>>>(h_a, rs, ew, dinv, b2, emb);
    k_out<<<(NN + 15) / 16, 256, 0, stream>>>(emb, Wl, bl, outp);
}

// Round 20
// 327.223 us; speedup vs baseline: 1.2601x; 1.0106x over previous
//
#include <hip/hip_runtime.h>

#define NN 100000
#define EE 1600000
#define IND 512
#define HIDD 128
#define OUTD 16
#define DEG_BLKS 192
#define GEMM_BLKS 1563  // ceil(NN/64)

typedef __bf16 bf16x8 __attribute__((ext_vector_type(8)));
typedef float f32x4 __attribute__((ext_vector_type(4)));

__device__ __forceinline__ ushort f2bf(float f) {
    union { float f; uint u; } v; v.f = f;
    uint r = v.u + 0x7FFFu + ((v.u >> 16) & 1u);
    return (ushort)(r >> 16);
}

__device__ __forceinline__ uint pk2bf(float a, float b) {
    __bf16 x = (__bf16)a, y = (__bf16)b;
    ushort ux = *(ushort*)&x, uy = *(ushort*)&y;
    return (uint)ux | ((uint)uy << 16);
}

#define GLDS16(src, dst)                                              \
    __builtin_amdgcn_global_load_lds(                                 \
        (const __attribute__((address_space(1))) void*)(src),         \
        (__attribute__((address_space(3))) void*)(dst), 16, 0, 0)

// ---------------- W prep + deg zeroing ----------------
__global__ void k_prep(const float* __restrict__ W1, const float* __restrict__ W2,
                       ushort* __restrict__ Wt1, ushort* __restrict__ Wt2,
                       int* __restrict__ deg) {
    int b = blockIdx.x, tid = threadIdx.x;
    if (b < 256) {
        int i = b * 256 + tid;
        int k = i >> 7, n = i & 127;
        Wt1[n * 512 + k] = f2bf(W1[i]);
    } else if (b < 320) {
        int i = (b - 256) * 256 + tid;
        int k = i >> 7, n = i & 127;
        Wt2[n * 128 + k] = f2bf(W2[i]);
    } else {
        int i = (b - 320) * 256 + tid;
        if (i < NN) deg[i] = 0;
    }
}

// ---------------- scan phase 1 ----------------
__global__ void k_scan_local(const int* __restrict__ deg, int* __restrict__ incl,
                             int* __restrict__ bsum) {
    __shared__ int s[256];
    int tid = threadIdx.x;
    int i = blockIdx.x * 256 + tid;
    int v = (i < NN) ? deg[i] : 0;
    s[tid] = v;
    __syncthreads();
    for (int off = 1; off < 256; off <<= 1) {
        int t = (tid >= off) ? s[tid - off] : 0;
        __syncthreads();
        s[tid] += t;
        __syncthreads();
    }
    if (i < NN) incl[i] = s[tid];
    if (tid == 255) bsum[blockIdx.x] = s[255];
}

// ---------------- scan phase 2 (per-block bsum prefix; norm fused) ----------------
__global__ void k_scan_final(const int* __restrict__ incl, const int* __restrict__ deg,
                             const int* __restrict__ bsum, int* __restrict__ rs,
                             float* __restrict__ dis, float* __restrict__ dinv) {
    __shared__ int red[256];
    int tid = threadIdx.x;
    int blk = blockIdx.x;
    int part = 0;
    for (int j = tid; j < blk; j += 256) part += bsum[j];
    red[tid] = part;
    __syncthreads();
    for (int off = 128; off > 0; off >>= 1) {
        if (tid < off) red[tid] += red[tid + off];
        __syncthreads();
    }
    int boff = red[0];

    int i = blk * 256 + tid;
    if (i < NN) {
        int d = deg[i];
        int v = incl[i] + boff;
        rs[i] = v - d;
        if (i == NN - 1) rs[NN] = v;
        float df = (float)(d + 1);
        dis[i] = rsqrtf(df);
        dinv[i] = 1.0f / df;
    }
}

// ---------------- CSR fill: atomic-free ----------------
__global__ void k_fill(const int* __restrict__ src, const int* __restrict__ dst,
                       const int* __restrict__ pos, const int* __restrict__ rs,
                       const float* __restrict__ dis, int2* __restrict__ ew) {
    int i = blockIdx.x * blockDim.x + threadIdx.x;
    int stride = gridDim.x * blockDim.x;
    for (; i < EE; i += stride) {
        int d = dst[i];
        int s = src[i];
        ew[rs[d] + pos[i]] = make_int2(s, __float_as_int(dis[s] * dis[d]));
    }
}

// ---------------- bf16 MFMA GEMM body: triple-buffered DMA, 2 stages in flight ----------------
// BM=64, BK=32, 4 waves. Ring of 3 {A,W} buffers; prologue issues stages 0,1;
// steady state keeps 2 stages (32KB) outstanding -> 96KB in flight per CU at
// 3 blocks/CU (vs R9's 80KB at 5 blocks, depth 1).
template <int K, bool AFP32>
__device__ __forceinline__ void gemm_body(const void* __restrict__ Ap,
                                          const ushort* __restrict__ Wt,
                                          ushort* __restrict__ C, int M, int blk) {
    constexpr int NT = K / 32;
    constexpr int ABYTES = AFP32 ? 64 * 32 * 4 : 64 * 32 * 2;
    constexpr int WBYTES = 128 * 32 * 2;
    constexpr int BUFB = ABYTES + WBYTES;
    __shared__ char smem[3 * BUFB];

    int tid = threadIdx.x;
    int row0 = blk * 64;
    int wid = tid >> 6, lane = tid & 63;
    int wm = wid * 16;
    int lm = lane & 15, lk8 = (lane >> 4) * 8;

    const float* Af = (const float*)Ap;
    const ushort* Ab16 = (const ushort*)Ap;

    f32x4 acc[8];
#pragma unroll
    for (int q = 0; q < 8; q++) acc[q] = (f32x4){0.f, 0.f, 0.f, 0.f};

    auto stage = [&](int bi, int k0) {
        char* Abase = smem + bi * BUFB;
        char* Wbase = Abase + ABYTES;
        if (AFP32) {
#pragma unroll
            for (int j = 0; j < 2; j++) {
                int c = wid * 2 + j;
                int rp = c * 8 + (lane >> 3);
                int sl = (lane & 7) ^ (rp & 7);
                int gr2 = row0 + rp; if (gr2 >= M) gr2 = M - 1;
                GLDS16(Af + (size_t)gr2 * K + k0 + sl * 4, Abase + c * 1024);
            }
        } else {
            int c = wid;
            int rp = c * 16 + (lane >> 2);
            int sl = (lane & 3) ^ (rp & 3);
            int gr2 = row0 + rp; if (gr2 >= M) gr2 = M - 1;
            GLDS16(Ab16 + (size_t)gr2 * K + k0 + sl * 8, Abase + c * 1024);
        }
#pragma unroll
        for (int j = 0; j < 2; j++) {
            int c = wid * 2 + j;
            int rp = c * 16 + (lane >> 2);
            int sl = (lane & 3) ^ (rp & 3);
            GLDS16(Wt + (size_t)rp * K + k0 + sl * 8, Wbase + c * 1024);
        }
    };

    stage(0, 0);
    if (NT > 1) stage(1, 32);

    int cur = 0;
    for (int t = 0; t < NT; t++) {
        if (t + 2 < NT) {
            int bi = cur + 2; if (bi >= 3) bi -= 3;
            stage(bi, (t + 2) * 32);
            // two stages (t+1, t+2) stay in flight
            if (AFP32) asm volatile("s_waitcnt vmcnt(8)" ::: "memory");
            else       asm volatile("s_waitcnt vmcnt(6)" ::: "memory");
        } else if (t + 1 < NT) {
            if (AFP32) asm volatile("s_waitcnt vmcnt(4)" ::: "memory");
            else       asm volatile("s_waitcnt vmcnt(3)" ::: "memory");
        } else {
            asm volatile("s_waitcnt vmcnt(0)" ::: "memory");
        }
        __builtin_amdgcn_s_barrier();

        char* Abase = smem + cur * BUFB;
        char* Wbase = Abase + ABYTES;
        bf16x8 xf, wf[8];
        if (AFP32) {
            int r_ = wm + lm;
            int s0 = lk8 >> 2;
            f32x4 a0 = *(const f32x4*)(Abase + r_ * 128 + (((s0)     ^ (r_ & 7)) << 4));
            f32x4 a1 = *(const f32x4*)(Abase + r_ * 128 + (((s0 + 1) ^ (r_ & 7)) << 4));
            uint4 u;
            u.x = pk2bf(a0[0], a0[1]);
            u.y = pk2bf(a0[2], a0[3]);
            u.z = pk2bf(a1[0], a1[1]);
            u.w = pk2bf(a1[2], a1[3]);
            xf = *(bf16x8*)&u;
        } else {
            int r_ = wm + lm;
            int s = lk8 >> 3;
            uint4 u = *(const uint4*)(Abase + r_ * 64 + ((s ^ (r_ & 3)) << 4));
            xf = *(bf16x8*)&u;
        }
#pragma unroll
        for (int q = 0; q < 8; q++) {
            int n_ = q * 16 + lm;
            int s = lk8 >> 3;
            uint4 u = *(const uint4*)(Wbase + n_ * 64 + ((s ^ (n_ & 3)) << 4));
            wf[q] = *(bf16x8*)&u;
        }
#pragma unroll
        for (int q = 0; q < 8; q++)
            acc[q] = __builtin_amdgcn_mfma_f32_16x16x32_bf16(wf[q], xf, acc[q], 0, 0, 0);

        asm volatile("" ::: "memory");
        __builtin_amdgcn_s_barrier();
        cur = (cur + 1 < 3) ? cur + 1 : 0;
    }

    int cn4 = (lane >> 4) * 4;
    int m = row0 + wm + lm;
    if (m < M) {
#pragma unroll
        for (int q = 0; q < 8; q++) {
            int n = q * 16 + cn4;
            uint2 o;
            o.x = (uint)f2bf(acc[q][0]) | ((uint)f2bf(acc[q][1]) << 16);
            o.y = (uint)f2bf(acc[q][2]) | ((uint)f2bf(acc[q][3]) << 16);
            *(uint2*)(C + (size_t)m * 128 + n) = o;
        }
    }
}

// mega1: blocks [0,DEG_BLKS) do deg+pos; rest do GEMM1.
__global__ __launch_bounds__(256, 3) void k_mega1(const float* __restrict__ x,
                                                  const ushort* __restrict__ Wt1,
                                                  ushort* __restrict__ C,
                                                  const int* __restrict__ dst,
                                                  int* __restrict__ deg,
                                                  int* __restrict__ pos) {
    if (blockIdx.x < DEG_BLKS) {
        int i = blockIdx.x * 256 + threadIdx.x;
        int stride = DEG_BLKS * 256;
        for (; i < EE; i += stride) pos[i] = atomicAdd(&deg[dst[i]], 1);
    } else {
        gemm_body<IND, true>(x, Wt1, C, NN, blockIdx.x - DEG_BLKS);
    }
}

__global__ __launch_bounds__(256, 4) void k_gemm2(const ushort* __restrict__ A,
                                                  const ushort* __restrict__ Wt,
                                                  ushort* __restrict__ C) {
    gemm_body<HIDD, false>(A, Wt, C, NN, blockIdx.x);
}

// ---------------- aggregation: half-wave per node, quarter-wave edge streams ----------------
template <bool OUTF32>
__global__ __launch_bounds__(256) void k_agg(const ushort* __restrict__ h,
                                             const int* __restrict__ rs,
                                             const int2* __restrict__ ew,
                                             const float* __restrict__ dinv,
                                             const float* __restrict__ bias,
                                             void* __restrict__ yv) {
    int tid = threadIdx.x;
    int node = blockIdx.x * 8 + (tid >> 5);
    if (node >= NN) return;
    int hl = tid & 31;
    int q = hl >> 4;
    int c = hl & 15;
    const uint4* h128 = (const uint4*)h;

    float a0 = 0.f, a1 = 0.f, a2 = 0.f, a3 = 0.f, a4 = 0.f, a5 = 0.f, a6 = 0.f, a7 = 0.f;
    if (q == 0) {
        float dv = dinv[node];
        uint4 sv = h128[(size_t)node * 16 + c];
        a0 = __uint_as_float(sv.x << 16) * dv; a1 = __uint_as_float(sv.x & 0xffff0000u) * dv;
        a2 = __uint_as_float(sv.y << 16) * dv; a3 = __uint_as_float(sv.y & 0xffff0000u) * dv;
        a4 = __uint_as_float(sv.z << 16) * dv; a5 = __uint_as_float(sv.z & 0xffff0000u) * dv;
        a6 = __uint_as_float(sv.w << 16) * dv; a7 = __uint_as_float(sv.w & 0xffff0000u) * dv;
    }

    int e = rs[node], e1 = rs[node + 1];

#define EL(i) int2 p##i = ew[e + 2 * i + q]; \
              uint4 g##i = h128[(size_t)(uint)p##i.x * 16 + c];
#define EA(i) { float w##i = __int_as_float(p##i.y); \
    a0 += w##i * __uint_as_float(g##i.x << 16); \
    a1 += w##i * __uint_as_float(g##i.x & 0xffff0000u); \
    a2 += w##i * __uint_as_float(g##i.y << 16); \
    a3 += w##i * __uint_as_float(g##i.y & 0xffff0000u); \
    a4 += w##i * __uint_as_float(g##i.z << 16); \
    a5 += w##i * __uint_as_float(g##i.z & 0xffff0000u); \
    a6 += w##i * __uint_as_float(g##i.w << 16); \
    a7 += w##i * __uint_as_float(g##i.w & 0xffff0000u); }

    for (; e + 16 <= e1; e += 16) {
        EL(0) EL(1) EL(2) EL(3) EL(4) EL(5) EL(6) EL(7)
        EA(0) EA(1) EA(2) EA(3) EA(4) EA(5) EA(6) EA(7)
    }
    for (; e + 4 <= e1; e += 4) {
        EL(0) EL(1)
        EA(0) EA(1)
    }
    if (e + 2 <= e1) {
        EL(0)
        EA(0)
        e += 2;
    }
    if (e < e1 && q == 0) {
        int2 p = ew[e];
        uint4 g = h128[(size_t)(uint)p.x * 16 + c];
        float w = __int_as_float(p.y);
        a0 += w * __uint_as_float(g.x << 16); a1 += w * __uint_as_float(g.x & 0xffff0000u);
        a2 += w * __uint_as_float(g.y << 16); a3 += w * __uint_as_float(g.y & 0xffff0000u);
        a4 += w * __uint_as_float(g.z << 16); a5 += w * __uint_as_float(g.z & 0xffff0000u);
        a6 += w * __uint_as_float(g.w << 16); a7 += w * __uint_as_float(g.w & 0xffff0000u);
    }
#undef EL
#undef EA

    a0 += __shfl_xor(a0, 16, 64); a1 += __shfl_xor(a1, 16, 64);
    a2 += __shfl_xor(a2, 16, 64); a3 += __shfl_xor(a3, 16, 64);
    a4 += __shfl_xor(a4, 16, 64); a5 += __shfl_xor(a5, 16, 64);
    a6 += __shfl_xor(a6, 16, 64); a7 += __shfl_xor(a7, 16, 64);

    if (q == 0) {
        float4 b0 = *(const float4*)(bias + c * 8);
        float4 b1 = *(const float4*)(bias + c * 8 + 4);
        a0 = fmaxf(a0 + b0.x, 0.f); a1 = fmaxf(a1 + b0.y, 0.f);
        a2 = fmaxf(a2 + b0.z, 0.f); a3 = fmaxf(a3 + b0.w, 0.f);
        a4 = fmaxf(a4 + b1.x, 0.f); a5 = fmaxf(a5 + b1.y, 0.f);
        a6 = fmaxf(a6 + b1.z, 0.f); a7 = fmaxf(a7 + b1.w, 0.f);
        if (OUTF32) {
            float* y = (float*)yv + (size_t)node * 128 + c * 8;
            *(float4*)(y)     = make_float4(a0, a1, a2, a3);
            *(float4*)(y + 4) = make_float4(a4, a5, a6, a7);
        } else {
            uint4 o;
            o.x = (uint)f2bf(a0) | ((uint)f2bf(a1) << 16);
            o.y = (uint)f2bf(a2) | ((uint)f2bf(a3) << 16);
            o.z = (uint)f2bf(a4) | ((uint)f2bf(a5) << 16);
            o.w = (uint)f2bf(a6) | ((uint)f2bf(a7) << 16);
            *(uint4*)((ushort*)yv + (size_t)node * 128 + c * 8) = o;
        }
    }
}

// ---------------- head: out[N][16] = emb[N][128] @ Wl[128][16] + bl ----------------
__global__ __launch_bounds__(256) void k_out(const float* __restrict__ emb,
                                             const float* __restrict__ Wl,
                                             const float* __restrict__ bl,
                                             float* __restrict__ out) {
    __shared__ float wl_s[128 * 16];
    __shared__ float es[16][129];
    int tid = threadIdx.x;
    int row0 = blockIdx.x * 16;
#pragma unroll
    for (int p = 0; p < 8; p++) wl_s[p * 256 + tid] = Wl[p * 256 + tid];
#pragma unroll
    for (int p = 0; p < 8; p++) {
        int idx = p * 256 + tid;
        int r = idx >> 7, c = idx & 127;
        int gr = row0 + r;
        es[r][c] = (gr < NN) ? emb[(size_t)gr * 128 + c] : 0.0f;
    }
    __syncthreads();
    int r = tid >> 4, o = tid & 15;
    float acc = bl[o];
#pragma unroll
    for (int k = 0; k < 128; k++) acc += es[r][k] * wl_s[k * 16 + o];
    int gr = row0 + r;
    if (gr < NN) out[(size_t)gr * 16 + o] = acc;
}

extern "C" void kernel_launch(void* const* d_in, const int* in_sizes, int n_in,
                              void* d_out, int out_size, void* d_ws, size_t ws_size,
                              hipStream_t stream) {
    const float* x  = (const float*)d_in[0];
    const int* ei   = (const int*)d_in[1];
    const float* W1 = (const float*)d_in[2];
    const float* b1 = (const float*)d_in[3];
    const float* W2 = (const float*)d_in[4];
    const float* b2 = (const float*)d_in[5];
    const float* Wl = (const float*)d_in[6];
    const float* bl = (const float*)d_in[7];
    const int* src = ei;
    const int* dst = ei + EE;

    float* outp = (float*)d_out;
    float* emb  = outp + (size_t)NN * OUTD;

    int2* ew    = (int2*)d_ws;
    int* pos    = (int*)(ew + EE);
    ushort* h_a = (ushort*)(pos + EE);
    ushort* h_b = h_a + (size_t)NN * 128;
    ushort* Wt1 = h_b + (size_t)NN * 128;
    ushort* Wt2 = Wt1 + 128 * 512;
    int* deg    = (int*)(Wt2 + 128 * 128);
    float* dis  = (float*)(deg + NN);
    float* dinv = dis + NN;
    int* incl   = (int*)(dinv + NN);
    int* rs     = incl + NN;
    int* bsum   = rs + NN + 8;

    const int NB_N = (NN + 255) / 256;  // 391

    k_prep<<<320 + NB_N, 256, 0, stream>>>(W1, W2, Wt1, Wt2, deg);
    k_mega1<<<DEG_BLKS + GEMM_BLKS, 256, 0, stream>>>(x, Wt1, h_a, dst, deg, pos);
    k_scan_local<<<NB_N, 256, 0, stream>>>(deg, incl, bsum);
    k_scan_final<<<NB_N, 256, 0, stream>>>(incl, deg, bsum, rs, dis, dinv);
    k_fill<<<2048, 256, 0, stream>>>(src, dst, pos, rs, dis, ew);

    k_agg<false><<<(NN + 7) / 8, 256, 0, stream>>>(h_a, rs, ew, dinv, b1, h_b);
    k_gemm2<<<GEMM_BLKS, 256, 0, stream>>>(h_b, Wt2, h_a);
    k_agg<true><<<(NN + 7) / 8, 256, 0, stream>>>(h_a, rs, ew, dinv, b2, emb);
    k_out<<<(NN + 15) / 16, 256, 0, stream>>>(emb, Wl, bl, outp);
}